// Round 3
// baseline (54.777 us; speedup 1.0000x reference)
//
#include <hip/hip_runtime.h>

// Shared_Unit_NL (KG-MTL-C variant):
//   s_cnn[b] = <drug_kg[b], w_aa + w_ab>
//   s_kg [b] = <drug_kg[b], w_ba + w_bb>
//   out_cnn[b,i] = drug_cnn[b,i] * s_cnn[b] + d_cnn_bias[i]
//   out_kg [b,i] = drug_cnn[b,i] * s_kg [b] + d_kg_bias[i]
// fp32, B=65536, D=256. Memory-bound: 256 MB moved -> ~41 us floor.
//
// R3 = R2 with the nontemporal-store type fixed: the builtin requires a
// native clang vector type (ext_vector_type), not HIP_vector_type<float,4>.
//  - 32 lanes/row, 2 rows/wave (lane owns 8 floats): 5-step butterfly, one
//    chain serves two rows -> shorter dep chain per byte.
//  - nontemporal stores: outputs write-once -> keep inputs LLC-resident.

constexpr int BN = 65536;
constexpr int DN = 256;

typedef float f32x4 __attribute__((ext_vector_type(4)));

__global__ __launch_bounds__(256) void shared_unit_kernel(
    const float* __restrict__ drug_cnn,
    const float* __restrict__ drug_kg,
    const float* __restrict__ w_aa,
    const float* __restrict__ w_ab,
    const float* __restrict__ w_ba,
    const float* __restrict__ w_bb,
    const float* __restrict__ bias_cnn,
    const float* __restrict__ bias_kg,
    float* __restrict__ out)
{
    const int lane    = threadIdx.x & 63;
    const int half    = lane >> 5;        // which of the 2 rows this wave handles
    const int sublane = lane & 31;
    const int j       = sublane << 3;     // 8 floats per lane: [j, j+8)

    const int wid = (blockIdx.x * blockDim.x + threadIdx.x) >> 6;  // global wave id
    const int nw  = (gridDim.x * blockDim.x) >> 6;                 // total waves

    // Row-invariant data (tiny, L1-resident). Lane needs elements [j, j+8).
    const f32x4 waa0 = *(const f32x4*)(w_aa + j);
    const f32x4 waa1 = *(const f32x4*)(w_aa + j + 4);
    const f32x4 wab0 = *(const f32x4*)(w_ab + j);
    const f32x4 wab1 = *(const f32x4*)(w_ab + j + 4);
    const f32x4 wba0 = *(const f32x4*)(w_ba + j);
    const f32x4 wba1 = *(const f32x4*)(w_ba + j + 4);
    const f32x4 wbb0 = *(const f32x4*)(w_bb + j);
    const f32x4 wbb1 = *(const f32x4*)(w_bb + j + 4);

    const f32x4 wa0 = waa0 + wab0;
    const f32x4 wa1 = waa1 + wab1;
    const f32x4 wb0 = wba0 + wbb0;
    const f32x4 wb1 = wba1 + wbb1;

    const f32x4 bc0 = *(const f32x4*)(bias_cnn + j);
    const f32x4 bc1 = *(const f32x4*)(bias_cnn + j + 4);
    const f32x4 bk0 = *(const f32x4*)(bias_kg + j);
    const f32x4 bk1 = *(const f32x4*)(bias_kg + j + 4);

    float* __restrict__ out_cnn = out;
    float* __restrict__ out_kg  = out + (size_t)BN * DN;

    // Each wave handles rows {2p, 2p+1}; half selects which.
    for (int p = wid; p < BN / 2; p += nw) {
        const int b = (p << 1) + half;
        const size_t base = (size_t)b * DN + j;

        const f32x4 kg0 = *(const f32x4*)(drug_kg  + base);
        const f32x4 kg1 = *(const f32x4*)(drug_kg  + base + 4);
        const f32x4 cn0 = *(const f32x4*)(drug_cnn + base);
        const f32x4 cn1 = *(const f32x4*)(drug_cnn + base + 4);

        float sa = kg0.x * wa0.x + kg0.y * wa0.y + kg0.z * wa0.z + kg0.w * wa0.w
                 + kg1.x * wa1.x + kg1.y * wa1.y + kg1.z * wa1.z + kg1.w * wa1.w;
        float sb = kg0.x * wb0.x + kg0.y * wb0.y + kg0.z * wb0.z + kg0.w * wb0.w
                 + kg1.x * wb1.x + kg1.y * wb1.y + kg1.z * wb1.z + kg1.w * wb1.w;

        // 5-step butterfly within each 32-lane half (off<32 never crosses halves).
        #pragma unroll
        for (int off = 1; off < 32; off <<= 1) {
            sa += __shfl_xor(sa, off);
            sb += __shfl_xor(sb, off);
        }

        const f32x4 oc0 = cn0 * sa + bc0;
        const f32x4 oc1 = cn1 * sa + bc1;
        const f32x4 ok0 = cn0 * sb + bk0;
        const f32x4 ok1 = cn1 * sb + bk1;

        // Nontemporal: outputs are write-once, keep inputs LLC-resident.
        __builtin_nontemporal_store(oc0, (f32x4*)(out_cnn + base));
        __builtin_nontemporal_store(oc1, (f32x4*)(out_cnn + base + 4));
        __builtin_nontemporal_store(ok0, (f32x4*)(out_kg + base));
        __builtin_nontemporal_store(ok1, (f32x4*)(out_kg + base + 4));
    }
}

extern "C" void kernel_launch(void* const* d_in, const int* in_sizes, int n_in,
                              void* d_out, int out_size, void* d_ws, size_t ws_size,
                              hipStream_t stream) {
    const float* drug_cnn = (const float*)d_in[0];
    const float* drug_kg  = (const float*)d_in[1];
    const float* w_aa     = (const float*)d_in[2];
    const float* w_ab     = (const float*)d_in[3];
    const float* w_ba     = (const float*)d_in[4];
    const float* w_bb     = (const float*)d_in[5];
    const float* b_cnn    = (const float*)d_in[6];
    const float* b_kg     = (const float*)d_in[7];
    float* out = (float*)d_out;

    // 2048 blocks x 256 threads = 8192 waves; each wave does 4 row-pairs.
    dim3 grid(2048), block(256);
    hipLaunchKernelGGL(shared_unit_kernel, grid, block, 0, stream,
                       drug_cnn, drug_kg, w_aa, w_ab, w_ba, w_bb, b_cnn, b_kg, out);
}

// Round 4
// 45.861 us; speedup vs baseline: 1.1944x; 1.1944x over previous
//
#include <hip/hip_runtime.h>

// Shared_Unit_NL (KG-MTL-C variant):
//   s_cnn[b] = <drug_kg[b], w_aa + w_ab>
//   s_kg [b] = <drug_kg[b], w_ba + w_bb>
//   out_cnn[b,i] = drug_cnn[b,i] * s_cnn[b] + d_cnn_bias[i]
//   out_kg [b,i] = drug_cnn[b,i] * s_kg [b] + d_kg_bias[i]
// fp32, B=65536, D=256. Memory-bound: 256 MB moved -> ~41 us floor.
//
// R4 = R3 minus nontemporal stores (measured: nt stores INCREASED
// WRITE_SIZE 128->150 MB and regressed 46.6->54.8 us; they defeat L2
// write-combining on gfx950). Keep the 2-rows/wave structure:
//  - 32 lanes/row, 2 rows/wave (lane owns 8 floats): 5-step butterfly,
//    one reduce chain serves two rows.
//  - plain float4 stores through L2 (WRITE_SIZE was exactly 128 MB in R1).

constexpr int BN = 65536;
constexpr int DN = 256;

typedef float f32x4 __attribute__((ext_vector_type(4)));

__global__ __launch_bounds__(256) void shared_unit_kernel(
    const float* __restrict__ drug_cnn,
    const float* __restrict__ drug_kg,
    const float* __restrict__ w_aa,
    const float* __restrict__ w_ab,
    const float* __restrict__ w_ba,
    const float* __restrict__ w_bb,
    const float* __restrict__ bias_cnn,
    const float* __restrict__ bias_kg,
    float* __restrict__ out)
{
    const int lane    = threadIdx.x & 63;
    const int half    = lane >> 5;        // which of the 2 rows this wave handles
    const int sublane = lane & 31;
    const int j       = sublane << 3;     // 8 floats per lane: [j, j+8)

    const int wid = (blockIdx.x * blockDim.x + threadIdx.x) >> 6;  // global wave id
    const int nw  = (gridDim.x * blockDim.x) >> 6;                 // total waves

    // Row-invariant data (tiny, L1-resident). Lane needs elements [j, j+8).
    const f32x4 waa0 = *(const f32x4*)(w_aa + j);
    const f32x4 waa1 = *(const f32x4*)(w_aa + j + 4);
    const f32x4 wab0 = *(const f32x4*)(w_ab + j);
    const f32x4 wab1 = *(const f32x4*)(w_ab + j + 4);
    const f32x4 wba0 = *(const f32x4*)(w_ba + j);
    const f32x4 wba1 = *(const f32x4*)(w_ba + j + 4);
    const f32x4 wbb0 = *(const f32x4*)(w_bb + j);
    const f32x4 wbb1 = *(const f32x4*)(w_bb + j + 4);

    const f32x4 wa0 = waa0 + wab0;
    const f32x4 wa1 = waa1 + wab1;
    const f32x4 wb0 = wba0 + wbb0;
    const f32x4 wb1 = wba1 + wbb1;

    const f32x4 bc0 = *(const f32x4*)(bias_cnn + j);
    const f32x4 bc1 = *(const f32x4*)(bias_cnn + j + 4);
    const f32x4 bk0 = *(const f32x4*)(bias_kg + j);
    const f32x4 bk1 = *(const f32x4*)(bias_kg + j + 4);

    float* __restrict__ out_cnn = out;
    float* __restrict__ out_kg  = out + (size_t)BN * DN;

    // Each wave handles rows {2p, 2p+1}; half selects which.
    for (int p = wid; p < BN / 2; p += nw) {
        const int b = (p << 1) + half;
        const size_t base = (size_t)b * DN + j;

        const f32x4 kg0 = *(const f32x4*)(drug_kg  + base);
        const f32x4 kg1 = *(const f32x4*)(drug_kg  + base + 4);
        const f32x4 cn0 = *(const f32x4*)(drug_cnn + base);
        const f32x4 cn1 = *(const f32x4*)(drug_cnn + base + 4);

        float sa = kg0.x * wa0.x + kg0.y * wa0.y + kg0.z * wa0.z + kg0.w * wa0.w
                 + kg1.x * wa1.x + kg1.y * wa1.y + kg1.z * wa1.z + kg1.w * wa1.w;
        float sb = kg0.x * wb0.x + kg0.y * wb0.y + kg0.z * wb0.z + kg0.w * wb0.w
                 + kg1.x * wb1.x + kg1.y * wb1.y + kg1.z * wb1.z + kg1.w * wb1.w;

        // 5-step butterfly within each 32-lane half (off<32 never crosses halves).
        #pragma unroll
        for (int off = 1; off < 32; off <<= 1) {
            sa += __shfl_xor(sa, off);
            sb += __shfl_xor(sb, off);
        }

        const f32x4 oc0 = cn0 * sa + bc0;
        const f32x4 oc1 = cn1 * sa + bc1;
        const f32x4 ok0 = cn0 * sb + bk0;
        const f32x4 ok1 = cn1 * sb + bk1;

        *(f32x4*)(out_cnn + base)     = oc0;
        *(f32x4*)(out_cnn + base + 4) = oc1;
        *(f32x4*)(out_kg  + base)     = ok0;
        *(f32x4*)(out_kg  + base + 4) = ok1;
    }
}

extern "C" void kernel_launch(void* const* d_in, const int* in_sizes, int n_in,
                              void* d_out, int out_size, void* d_ws, size_t ws_size,
                              hipStream_t stream) {
    const float* drug_cnn = (const float*)d_in[0];
    const float* drug_kg  = (const float*)d_in[1];
    const float* w_aa     = (const float*)d_in[2];
    const float* w_ab     = (const float*)d_in[3];
    const float* w_ba     = (const float*)d_in[4];
    const float* w_bb     = (const float*)d_in[5];
    const float* b_cnn    = (const float*)d_in[6];
    const float* b_kg     = (const float*)d_in[7];
    float* out = (float*)d_out;

    // 2048 blocks x 256 threads = 8192 waves; each wave does 4 row-pairs.
    dim3 grid(2048), block(256);
    hipLaunchKernelGGL(shared_unit_kernel, grid, block, 0, stream,
                       drug_cnn, drug_kg, w_aa, w_ab, w_ba, w_bb, b_cnn, b_kg, out);
}